// Round 9
// baseline (253.805 us; speedup 1.0000x reference)
//
#include <hip/hip_runtime.h>
#include <hip/hip_bf16.h>

// out[b,o] = sum_n relu( (s[b]-v[n]) . W[n,o,:] + bias[n,o] )
//          = sum_n relu( s[b].W[n,o,:] + c[n,o] ),  c[n,o] = bias[n,o] - v[n].W[n,o,:]
//
// prep: per-(n, 64-o slab) LDS transpose of W -> bf16 fragment-order Wf:
//   1KB chunk per (n, oc16, kt); lane l holds o = oc16*16+(l&15), k = kt*32+(l>>4)*8
//   (exact 16x16x32 B-fragment). Also c = bias - v.W from the staged slab.
// main: BM=64 x BO=64, TPB=512, LDS 64KB -> 2 blocks/CU -> 4 waves/SIMD
//   (the r3..r8 wall was 2 waves/SIMD latency). Waves = 4 og x 2 mg; j=4, mi=2
//   -> 8 MFMA per 2 ds_reads; acc = 40 VGPR so the (512,4) 128-reg cap is SAFE
//   (r4/r5 failed because demand ~200 > cap; here demand ~110).
//   No n-split -> no reduction epilogue, direct coalesced stores.
//   Grid map pins each ob's 16 b-blocks to one XCD; they stream the same Wf
//   chunks in lockstep -> L2 temporal sharing for the 16x W re-read.
// fused: fp32-W fallback if ws too small.

typedef __attribute__((ext_vector_type(8)))  short bf16x8;
typedef __attribute__((ext_vector_type(4)))  float f32x4;

constexpr int B   = 1024;
constexpr int N   = 64;
constexpr int D   = 512;
constexpr int OUT = 2048;

constexpr int BM  = 64;     // rows per block
constexpr int BO  = 64;     // cols per block: 4 og x 16
constexpr int TPB = 512;    // 8 waves

static __device__ __forceinline__ unsigned short f2bf(float f) {
    unsigned int u = __builtin_bit_cast(unsigned int, f);
    u += 0x7FFFu + ((u >> 16) & 1u);
    return (unsigned short)(u >> 16);
}

static __device__ __forceinline__ float bf2f(unsigned short u) {
    unsigned int x = ((unsigned int)u) << 16;
    return __builtin_bit_cast(float, x);
}

static __device__ __forceinline__ bf16x8 cvt8(float4 a, float4 b) {
    bf16x8 r;
    r[0] = (short)f2bf(a.x); r[1] = (short)f2bf(a.y);
    r[2] = (short)f2bf(a.z); r[3] = (short)f2bf(a.w);
    r[4] = (short)f2bf(b.x); r[5] = (short)f2bf(b.y);
    r[6] = (short)f2bf(b.z); r[7] = (short)f2bf(b.w);
    return r;
}

// ---------------- prep: Wf (16-col fragment-order) + c, via LDS transpose ----------------
// grid = N * 32 blocks (one per (n, 64-o slab)), 256 threads.
__global__ __launch_bounds__(256) void prep_kernel(const float* __restrict__ W,
                                                   const float* __restrict__ V,
                                                   const float* __restrict__ bias,
                                                   unsigned short* __restrict__ Wf,
                                                   float* __restrict__ c) {
    __shared__ unsigned short L[64 * 512];   // 64 KiB, swizzled: kc ^ (r&15)

    const int nb = blockIdx.x;
    const int n  = nb >> 5;          // 0..63
    const int ob = nb & 31;          // 0..31
    const int t  = threadIdx.x;

    // ---- stage slab: W[n][ob*64 + r][k], coalesced fp32 reads -> bf16 LDS ----
    #pragma unroll
    for (int i = 0; i < 16; ++i) {
        const int cid = i * 256 + t;         // 4096 chunks of 8 elems
        const int r   = cid >> 6;            // 0..63
        const int kc  = cid & 63;            // 0..63
        const float4* wp = reinterpret_cast<const float4*>(
            W + ((size_t)n * OUT + ob * 64 + r) * D + kc * 8);
        bf16x8 v8 = cvt8(wp[0], wp[1]);
        *reinterpret_cast<bf16x8*>(&L[r * 512 + ((kc ^ (r & 15)) * 8)]) = v8;
    }
    __syncthreads();

    // ---- c[n, ob*64 + r] = bias - dot(v[n], row r of slab) ----
    if (t < 64) {
        const int r = t;
        float s = 0.f;
        #pragma unroll 8
        for (int kc = 0; kc < 64; ++kc) {
            bf16x8 wv = *reinterpret_cast<const bf16x8*>(&L[r * 512 + ((kc ^ (r & 15)) * 8)]);
            const float4 va = *reinterpret_cast<const float4*>(V + (size_t)n * D + kc * 8);
            const float4 vb = *reinterpret_cast<const float4*>(V + (size_t)n * D + kc * 8 + 4);
            s += bf2f((unsigned short)wv[0]) * va.x + bf2f((unsigned short)wv[1]) * va.y
               + bf2f((unsigned short)wv[2]) * va.z + bf2f((unsigned short)wv[3]) * va.w
               + bf2f((unsigned short)wv[4]) * vb.x + bf2f((unsigned short)wv[5]) * vb.y
               + bf2f((unsigned short)wv[6]) * vb.z + bf2f((unsigned short)wv[7]) * vb.w;
        }
        const int o = ob * 64 + r;
        c[n * OUT + o] = bias[n * OUT + o] - s;
    }

    // ---- write fragment-order chunks, coalesced 1KB/wave ----
    // chunk(n, oc16=ob*4+og, kt): lane l -> 16B of row og*16+(l&15), k kt*32+(l>>4)*8.
    const size_t obase = (size_t)(n * 128 + ob * 4) * 16 * 512;   // shorts
    #pragma unroll
    for (int i = 0; i < 16; ++i) {
        const int cid   = i * 256 + t;
        const int lane  = cid & 63;
        const int chunk = cid >> 6;          // 0..63 = og*16 + kt
        const int og    = chunk >> 4;
        const int kt    = chunk & 15;
        const int row   = og * 16 + (lane & 15);
        const int kc    = kt * 4 + (lane >> 4);
        bf16x8 v8 = *reinterpret_cast<const bf16x8*>(&L[row * 512 + ((kc ^ (row & 15)) * 8)]);
        *reinterpret_cast<bf16x8*>(&Wf[obase + (size_t)chunk * 512 + lane * 8]) = v8;
    }
}

// ---------------- main: 16x16x32 MFMA, 2 blocks/CU, direct stores ----------------
__global__ __launch_bounds__(TPB, 4) void main_kernel(const float* __restrict__ S,
                                                      const unsigned short* __restrict__ Wf,
                                                      const float* __restrict__ C,
                                                      float* __restrict__ out) {
    // A-tile: 64 rows x 512 k bf16, XOR-swizzled 16B chunks: kc ^ (row&15) -> 0 conflicts.
    __shared__ unsigned short As[BM * D];   // 64 KiB

    // Bijective grid map: XCD = bid&7 hosts ob in {x, x+8, x+16, x+24};
    // the 16 b-blocks of one ob stream identical Wf chunks -> L2 sharing.
    const int bid = blockIdx.x;
    const int ob  = (bid & 7) + 8 * ((bid >> 7) & 3);   // 0..31
    const int bm0 = ((bid >> 3) & 15) * BM;

    const int t    = threadIdx.x;
    const int lane = t & 63;
    const int w    = t >> 6;          // 0..7
    const int og   = w & 3;           // 16-col group
    const int mg   = w >> 2;          // 32-row group
    const int l15  = lane & 15;
    const int lg   = lane >> 4;       // 0..3
    const int ocol = ob * BO + og * 16 + l15;
    const int rb   = mg * 32;         // local row base

    // ---- stage A = S[bm0:bm0+64, :] as bf16 (once per block) ----
    #pragma unroll
    for (int i = 0; i < (BM * D / 8) / TPB; ++i) {   // 8 iters
        int cid = i * TPB + t;
        int row = cid >> 6;            // 64 chunks per row
        int kc  = cid & 63;
        const float4* sp = reinterpret_cast<const float4*>(S + (size_t)(bm0 + row) * D + kc * 8);
        bf16x8 val = cvt8(sp[0], sp[1]);
        *reinterpret_cast<bf16x8*>(&As[row * D + ((kc ^ (row & 15)) * 8)]) = val;
    }
    __syncthreads();

    f32x4 oacc[2];
    #pragma unroll
    for (int mi = 0; mi < 2; ++mi) oacc[mi] = (f32x4){0.f, 0.f, 0.f, 0.f};

    constexpr size_t NSTR = (size_t)128 * 16 * 512;   // per-n stride in shorts (2 MiB)

    for (int nc = 0; nc < 16; ++nc) {
        const int n0 = nc * 4;

        f32x4 pre[4][2];
        #pragma unroll
        for (int j = 0; j < 4; ++j)
            #pragma unroll
            for (int mi = 0; mi < 2; ++mi) pre[j][mi] = (f32x4){0.f, 0.f, 0.f, 0.f};

        // sequential 1KB-chunk stream per (n, oc16): base + ks*512 shorts.
        const unsigned short* wf0 =
            Wf + (size_t)(n0 * 128 + ob * 4 + og) * 16 * 512 + lane * 8;

        const int r0 = rb + l15;          // mi=0 row (row&15 == l15)
        const int r1 = rb + 16 + l15;     // mi=1 row

        #pragma unroll 2
        for (int ks = 0; ks < 16; ++ks) {
            bf16x8 bq0 = *reinterpret_cast<const bf16x8*>(wf0 + 0 * NSTR + ks * 512);
            bf16x8 bq1 = *reinterpret_cast<const bf16x8*>(wf0 + 1 * NSTR + ks * 512);
            bf16x8 bq2 = *reinterpret_cast<const bf16x8*>(wf0 + 2 * NSTR + ks * 512);
            bf16x8 bq3 = *reinterpret_cast<const bf16x8*>(wf0 + 3 * NSTR + ks * 512);

            const int kc   = ks * 4 + lg;
            bf16x8 aq0 = *reinterpret_cast<const bf16x8*>(&As[r0 * D + ((kc ^ l15) * 8)]);
            bf16x8 aq1 = *reinterpret_cast<const bf16x8*>(&As[r1 * D + ((kc ^ l15) * 8)]);

            pre[0][0] = __builtin_amdgcn_mfma_f32_16x16x32_bf16(aq0, bq0, pre[0][0], 0, 0, 0);
            pre[0][1] = __builtin_amdgcn_mfma_f32_16x16x32_bf16(aq1, bq0, pre[0][1], 0, 0, 0);
            pre[1][0] = __builtin_amdgcn_mfma_f32_16x16x32_bf16(aq0, bq1, pre[1][0], 0, 0, 0);
            pre[1][1] = __builtin_amdgcn_mfma_f32_16x16x32_bf16(aq1, bq1, pre[1][1], 0, 0, 0);
            pre[2][0] = __builtin_amdgcn_mfma_f32_16x16x32_bf16(aq0, bq2, pre[2][0], 0, 0, 0);
            pre[2][1] = __builtin_amdgcn_mfma_f32_16x16x32_bf16(aq1, bq2, pre[2][1], 0, 0, 0);
            pre[3][0] = __builtin_amdgcn_mfma_f32_16x16x32_bf16(aq0, bq3, pre[3][0], 0, 0, 0);
            pre[3][1] = __builtin_amdgcn_mfma_f32_16x16x32_bf16(aq1, bq3, pre[3][1], 0, 0, 0);
        }

        #pragma unroll
        for (int j = 0; j < 4; ++j) {
            const float cv = C[(n0 + j) * OUT + ocol];
            #pragma unroll
            for (int mi = 0; mi < 2; ++mi)
                #pragma unroll
                for (int r = 0; r < 4; ++r)
                    oacc[mi][r] += fmaxf(pre[j][mi][r] + cv, 0.f);
        }
    }

    // ---- direct store: C/D layout col = lane&15, row = lg*4 + q ----
    #pragma unroll
    for (int mi = 0; mi < 2; ++mi) {
        #pragma unroll
        for (int q = 0; q < 4; ++q) {
            const int row = bm0 + rb + mi * 16 + lg * 4 + q;
            out[(size_t)row * OUT + ocol] = oacc[mi][q];
        }
    }
}

// ---------------- fallback: fused fp32-W kernel (r2-proven) ----------------
__global__ __launch_bounds__(512) void fused_kernel(const float* __restrict__ S,
                                                    const float* __restrict__ W,
                                                    const float* __restrict__ V,
                                                    const float* __restrict__ bias,
                                                    float* __restrict__ out) {
    __shared__ unsigned short As3[128 * D];

    const int t    = threadIdx.x;
    const int lane = t & 63;
    const int w    = t >> 6;
    const int og   = w & 3;
    const int ngh  = w >> 2;
    const int l15  = lane & 15;
    const int lg   = lane >> 4;
    const int ob0  = blockIdx.x * 64;
    const int bm0  = blockIdx.y * 128;
    const int ocol = ob0 + og * 16 + l15;

    #pragma unroll
    for (int i = 0; i < (128 * D / 8) / 512; ++i) {
        int cid = i * 512 + t;
        int row = cid >> 6;
        int kc  = cid & 63;
        const float4* sp = reinterpret_cast<const float4*>(S + (size_t)(bm0 + row) * D + kc * 8);
        bf16x8 val = cvt8(sp[0], sp[1]);
        *reinterpret_cast<bf16x8*>(&As3[row * D + ((kc ^ (row & 7)) * 8)]) = val;
    }
    __syncthreads();

    f32x4 oacc[8];
    #pragma unroll
    for (int mi = 0; mi < 8; ++mi) oacc[mi] = (f32x4){0.f, 0.f, 0.f, 0.f};

    const int kofs = lg * 8;

    for (int nc = 0; nc < 8; ++nc) {
        const int n0 = ngh * 32 + nc * 4;

        f32x4 pre[4][8];
        #pragma unroll
        for (int j = 0; j < 4; ++j)
            #pragma unroll
            for (int mi = 0; mi < 8; ++mi) pre[j][mi] = (f32x4){0.f, 0.f, 0.f, 0.f};

        float cacc[4] = {0.f, 0.f, 0.f, 0.f};

        const float* wbase = W + ((size_t)n0 * OUT + ocol) * D + kofs;
        const float* vbase = V + (size_t)n0 * D + kofs;

        #pragma unroll 2
        for (int ks = 0; ks < 16; ++ks) {
            bf16x8 bq[4];
            #pragma unroll
            for (int j = 0; j < 4; ++j) {
                const float* wr = wbase + (size_t)j * (OUT * D) + ks * 32;
                float4 wa = *reinterpret_cast<const float4*>(wr);
                float4 wb = *reinterpret_cast<const float4*>(wr + 4);
                const float* vr = vbase + (size_t)j * D + ks * 32;
                float4 va = *reinterpret_cast<const float4*>(vr);
                float4 vb = *reinterpret_cast<const float4*>(vr + 4);
                cacc[j] += wa.x * va.x + wa.y * va.y + wa.z * va.z + wa.w * va.w
                         + wb.x * vb.x + wb.y * vb.y + wb.z * vb.z + wb.w * vb.w;
                bq[j] = cvt8(wa, wb);
            }
            const int kc = ks * 4 + lg;
            #pragma unroll
            for (int mi = 0; mi < 8; ++mi) {
                const int row = mi * 16 + l15;
                bf16x8 aq = *reinterpret_cast<const bf16x8*>(
                    &As3[row * D + ((kc ^ (row & 7)) * 8)]);
                pre[0][mi] = __builtin_amdgcn_mfma_f32_16x16x32_bf16(aq, bq[0], pre[0][mi], 0, 0, 0);
                pre[1][mi] = __builtin_amdgcn_mfma_f32_16x16x32_bf16(aq, bq[1], pre[1][mi], 0, 0, 0);
                pre[2][mi] = __builtin_amdgcn_mfma_f32_16x16x32_bf16(aq, bq[2], pre[2][mi], 0, 0, 0);
                pre[3][mi] = __builtin_amdgcn_mfma_f32_16x16x32_bf16(aq, bq[3], pre[3][mi], 0, 0, 0);
            }
        }

        #pragma unroll
        for (int j = 0; j < 4; ++j) {
            float cs = cacc[j];
            cs += __shfl_xor(cs, 16);
            cs += __shfl_xor(cs, 32);
            const float cv = bias[(n0 + j) * OUT + ocol] - cs;
            #pragma unroll
            for (int mi = 0; mi < 8; ++mi)
                #pragma unroll
                for (int r = 0; r < 4; ++r)
                    oacc[mi][r] += fmaxf(pre[j][mi][r] + cv, 0.f);
        }
    }

    __syncthreads();
    float* red = reinterpret_cast<float*>(As3);
    if (ngh == 1) {
        #pragma unroll
        for (int mi = 0; mi < 8; ++mi)
            *reinterpret_cast<f32x4*>(&red[(og * 8 + mi) * 256 + lane * 4]) = oacc[mi];
    }
    __syncthreads();
    if (ngh == 0) {
        #pragma unroll
        for (int mi = 0; mi < 8; ++mi) {
            f32x4 o2 = *reinterpret_cast<const f32x4*>(&red[(og * 8 + mi) * 256 + lane * 4]);
            #pragma unroll
            for (int r = 0; r < 4; ++r) {
                int row = bm0 + mi * 16 + lg * 4 + r;
                out[(size_t)row * OUT + ocol] = oacc[mi][r] + o2[r];
            }
        }
    }
}

extern "C" void kernel_launch(void* const* d_in, const int* in_sizes, int n_in,
                              void* d_out, int out_size, void* d_ws, size_t ws_size,
                              hipStream_t stream) {
    const float* S    = (const float*)d_in[0];   // semantic_vec [B, D]
    const float* V    = (const float*)d_in[1];   // vertices     [N, D]
    const float* W    = (const float*)d_in[2];   // W            [N, OUT, D]
    const float* bias = (const float*)d_in[3];   // b            [N, OUT]
    float* out = (float*)d_out;                  // [B, OUT] f32

    const size_t wb_bytes = (size_t)N * OUT * D * sizeof(unsigned short); // 128 MiB
    const size_t c_bytes  = (size_t)N * OUT * sizeof(float);              // 512 KiB

    if (ws_size >= wb_bytes + c_bytes) {
        unsigned short* Wf = (unsigned short*)d_ws;
        float*          c  = (float*)((char*)d_ws + wb_bytes);
        prep_kernel<<<dim3(N * 32), dim3(256), 0, stream>>>(W, V, bias, Wf, c);
        main_kernel<<<dim3((OUT / BO) * (B / BM)), dim3(TPB), 0, stream>>>(S, Wf, c, out);
    } else {
        fused_kernel<<<dim3(OUT / 64, B / 128), dim3(512), 0, stream>>>(S, W, V, bias, out);
    }
}